// Round 1
// baseline (1469.365 us; speedup 1.0000x reference)
//
#include <hip/hip_runtime.h>
#include <math.h>

#define NN    50000
#define FDIM  200
#define E1N   400000
#define E2N   100000
#define EN    500000

// ---------------- workspace layout (floats) ----------------
// vall   [600]          @ 0
// wall   [600]          @ 600
// scal   [NN*4]         @ 1200        (ps,pd,qs,qd per node)
// Xs     [NN*200]       @ 201200
// rowsum [NN]           @ 10201200    (zeroed)
// T      [NN*400]       @ 10251200    (zeroed)
#define VALL_OFF   0
#define WALL_OFF   600
#define SCAL_OFF   1200
#define XS_OFF     201200
#define RS_OFF     10201200
#define T_OFF      10251200

// v_all[k] = sum_o a_2[o]*a[o][k] ; w_all[k] = sum_o mlp_w[o]*a[o][k]
__global__ void k_coeffs(const float* __restrict__ a, const float* __restrict__ a2,
                         const float* __restrict__ mlpw,
                         float* __restrict__ vall, float* __restrict__ wall) {
    int k = blockIdx.x * blockDim.x + threadIdx.x;
    if (k >= 600) return;
    float v = 0.f, w = 0.f;
    for (int o = 0; o < FDIM; ++o) {
        float av = a[o * 600 + k];
        v += a2[o] * av;
        w += mlpw[o] * av;
    }
    vall[k] = v;
    wall[k] = w;
}

// per-node scalars: ps=dot(x[n],v[0:200]) pd=dot(x[n],v[200:400])
//                   qs=dot(x[n],w[0:200]) qd=dot(x[n],w[200:400])
__global__ __launch_bounds__(256) void k_node_scal(const float* __restrict__ x,
                                                   const float* __restrict__ vall,
                                                   const float* __restrict__ wall,
                                                   float* __restrict__ scal) {
    __shared__ float sv[1200];
    int tid = threadIdx.x;
    for (int i = tid; i < 1200; i += 256) sv[i] = (i < 600) ? vall[i] : wall[i - 600];
    __syncthreads();
    int lane = tid & 63;
    int n = blockIdx.x * 4 + (tid >> 6);
    float ps = 0.f, pd = 0.f, qs = 0.f, qd = 0.f;
    for (int k = lane; k < FDIM; k += 64) {
        float xv = x[(size_t)n * FDIM + k];
        ps += xv * sv[k];
        pd += xv * sv[200 + k];
        qs += xv * sv[600 + k];
        qd += xv * sv[800 + k];
    }
    #pragma unroll
    for (int off = 32; off > 0; off >>= 1) {
        ps += __shfl_xor(ps, off);
        pd += __shfl_xor(pd, off);
        qs += __shfl_xor(qs, off);
        qd += __shfl_xor(qd, off);
    }
    if (lane == 0) {
        float4 r = make_float4(ps, pd, qs, qd);
        *(float4*)(scal + (size_t)n * 4) = r;
    }
}

// Xs = x @ A1^T   (A1 = a[:, 0:200], row stride 600)
__global__ __launch_bounds__(256) void k_gemm_xs(const float* __restrict__ X,
                                                 const float* __restrict__ Wm,
                                                 float* __restrict__ C) {
    __shared__ float Xl[16][68];
    __shared__ float Wl[16][68];
    int tid = threadIdx.x;
    int bx = blockIdx.x, by = blockIdx.y;
    int m_l = tid >> 2, k_l = (tid & 3) * 4;
    int tx = tid & 15, ty = tid >> 4;
    float acc[4][4] = {};
    for (int k0 = 0; k0 < FDIM; k0 += 16) {
        int row = by * 64 + m_l;
        float4 xv = make_float4(0.f, 0.f, 0.f, 0.f);
        if (row < NN && (k0 + k_l) < FDIM)
            xv = *(const float4*)(X + (size_t)row * FDIM + k0 + k_l);
        Xl[k_l + 0][m_l] = xv.x; Xl[k_l + 1][m_l] = xv.y;
        Xl[k_l + 2][m_l] = xv.z; Xl[k_l + 3][m_l] = xv.w;
        int nrow = bx * 64 + m_l;
        float4 wv = make_float4(0.f, 0.f, 0.f, 0.f);
        if (nrow < FDIM && (k0 + k_l) < FDIM)
            wv = *(const float4*)(Wm + (size_t)nrow * 600 + k0 + k_l);
        Wl[k_l + 0][m_l] = wv.x; Wl[k_l + 1][m_l] = wv.y;
        Wl[k_l + 2][m_l] = wv.z; Wl[k_l + 3][m_l] = wv.w;
        __syncthreads();
        #pragma unroll
        for (int kk = 0; kk < 16; ++kk) {
            float4 a4 = *(const float4*)&Xl[kk][ty * 4];
            float4 b4 = *(const float4*)&Wl[kk][tx * 4];
            acc[0][0] += a4.x * b4.x; acc[0][1] += a4.x * b4.y; acc[0][2] += a4.x * b4.z; acc[0][3] += a4.x * b4.w;
            acc[1][0] += a4.y * b4.x; acc[1][1] += a4.y * b4.y; acc[1][2] += a4.y * b4.z; acc[1][3] += a4.y * b4.w;
            acc[2][0] += a4.z * b4.x; acc[2][1] += a4.z * b4.y; acc[2][2] += a4.z * b4.z; acc[2][3] += a4.z * b4.w;
            acc[3][0] += a4.w * b4.x; acc[3][1] += a4.w * b4.y; acc[3][2] += a4.w * b4.z; acc[3][3] += a4.w * b4.w;
        }
        __syncthreads();
    }
    #pragma unroll
    for (int i = 0; i < 4; ++i) {
        int row = by * 64 + ty * 4 + i;
        if (row >= NN) continue;
        #pragma unroll
        for (int j = 0; j < 4; ++j) {
            int col = bx * 64 + tx * 4 + j;
            if (col < FDIM) C[(size_t)row * FDIM + col] = acc[i][j];
        }
    }
}

// per-edge: compute w_e, scatter w_e*[x[dst], emb] into T[src], w_e into rowsum[src]
__global__ __launch_bounds__(256) void k_edge(const int* __restrict__ edge,
                                              const float* __restrict__ ee,
                                              const int* __restrict__ edge_nh,
                                              const float* __restrict__ ee_nh,
                                              const float* __restrict__ x,
                                              const float* __restrict__ vall,
                                              const float* __restrict__ wall,
                                              const float* __restrict__ scal,
                                              const float* __restrict__ mlpb,
                                              float* __restrict__ rowsum,
                                              float* __restrict__ T) {
    __shared__ float sv[400];  // v3 | w3
    int tid = threadIdx.x;
    for (int i = tid; i < 400; i += 256)
        sv[i] = (i < 200) ? vall[400 + i] : wall[400 + (i - 200)];
    __syncthreads();
    int lane = tid & 63;
    int e = (blockIdx.x * 256 + tid) >> 6;
    int s, d;
    const float* erow;
    if (e < E1N) {
        s = edge[e]; d = edge[E1N + e];
        erow = ee + (size_t)e * FDIM;
    } else {
        int e2 = e - E1N;
        s = edge_nh[e2]; d = edge_nh[E2N + e2];
        erow = ee_nh + (size_t)e2 * FDIM;
    }
    float er[4];
    float pe = 0.f, qe = 0.f;
    #pragma unroll
    for (int i = 0; i < 4; ++i) {
        int k = lane + 64 * i;
        float v = (k < FDIM) ? erow[k] : 0.f;
        er[i] = v;
        if (k < FDIM) { pe += v * sv[k]; qe += v * sv[200 + k]; }
    }
    #pragma unroll
    for (int off = 32; off > 0; off >>= 1) {
        pe += __shfl_xor(pe, off);
        qe += __shfl_xor(qe, off);
    }
    float4 sc_s = *(const float4*)(scal + (size_t)s * 4);
    float4 sc_d = *(const float4*)(scal + (size_t)d * 4);
    float z1 = sc_s.x + sc_d.y + pe;             // edge_m . a_2
    float z2 = sc_s.z + sc_d.w + qe + mlpb[0];   // edge_m . mlp_w + b
    float l = z1 > 0.f ? z1 : 0.2f * z1;         // leakyrelu
    float w = expf((-l) * tanhf(z2) * (1.0f / (float)EN));
    if (lane == 0) atomicAdd(rowsum + s, w);
    float* Trow = T + (size_t)s * 400;
    #pragma unroll
    for (int i = 0; i < 4; ++i) {
        int k = lane + 64 * i;
        if (k < FDIM) {
            float xv = x[(size_t)d * FDIM + k];
            atomicAdd(Trow + k, w * xv);
            atomicAdd(Trow + 200 + k, w * er[i]);
        }
    }
}

// out = elu(Xs + (T @ [A2;A3]^T)/rowsum) ; zero-edge nodes -> 0
__global__ __launch_bounds__(256) void k_gemm_out(const float* __restrict__ X,   // T [NN,400]
                                                  const float* __restrict__ Wm,  // a+200, stride 600
                                                  const float* __restrict__ Xs,
                                                  const float* __restrict__ rowsum,
                                                  float* __restrict__ out) {
    __shared__ float Xl[16][68];
    __shared__ float Wl[16][68];
    int tid = threadIdx.x;
    int bx = blockIdx.x, by = blockIdx.y;
    int m_l = tid >> 2, k_l = (tid & 3) * 4;
    int tx = tid & 15, ty = tid >> 4;
    float acc[4][4] = {};
    for (int k0 = 0; k0 < 400; k0 += 16) {
        int row = by * 64 + m_l;
        float4 xv = make_float4(0.f, 0.f, 0.f, 0.f);
        if (row < NN)
            xv = *(const float4*)(X + (size_t)row * 400 + k0 + k_l);
        Xl[k_l + 0][m_l] = xv.x; Xl[k_l + 1][m_l] = xv.y;
        Xl[k_l + 2][m_l] = xv.z; Xl[k_l + 3][m_l] = xv.w;
        int nrow = bx * 64 + m_l;
        float4 wv = make_float4(0.f, 0.f, 0.f, 0.f);
        if (nrow < FDIM)
            wv = *(const float4*)(Wm + (size_t)nrow * 600 + k0 + k_l);
        Wl[k_l + 0][m_l] = wv.x; Wl[k_l + 1][m_l] = wv.y;
        Wl[k_l + 2][m_l] = wv.z; Wl[k_l + 3][m_l] = wv.w;
        __syncthreads();
        #pragma unroll
        for (int kk = 0; kk < 16; ++kk) {
            float4 a4 = *(const float4*)&Xl[kk][ty * 4];
            float4 b4 = *(const float4*)&Wl[kk][tx * 4];
            acc[0][0] += a4.x * b4.x; acc[0][1] += a4.x * b4.y; acc[0][2] += a4.x * b4.z; acc[0][3] += a4.x * b4.w;
            acc[1][0] += a4.y * b4.x; acc[1][1] += a4.y * b4.y; acc[1][2] += a4.y * b4.z; acc[1][3] += a4.y * b4.w;
            acc[2][0] += a4.z * b4.x; acc[2][1] += a4.z * b4.y; acc[2][2] += a4.z * b4.z; acc[2][3] += a4.z * b4.w;
            acc[3][0] += a4.w * b4.x; acc[3][1] += a4.w * b4.y; acc[3][2] += a4.w * b4.z; acc[3][3] += a4.w * b4.w;
        }
        __syncthreads();
    }
    #pragma unroll
    for (int i = 0; i < 4; ++i) {
        int row = by * 64 + ty * 4 + i;
        if (row >= NN) continue;
        float rs = rowsum[row];
        #pragma unroll
        for (int j = 0; j < 4; ++j) {
            int col = bx * 64 + tx * 4 + j;
            if (col < FDIM) {
                float o;
                if (rs == 0.f) {
                    o = 0.f;
                } else {
                    float h = Xs[(size_t)row * FDIM + col] + acc[i][j] / rs;
                    o = h > 0.f ? h : expm1f(h);
                }
                out[(size_t)row * FDIM + col] = o;
            }
        }
    }
}

extern "C" void kernel_launch(void* const* d_in, const int* in_sizes, int n_in,
                              void* d_out, int out_size, void* d_ws, size_t ws_size,
                              hipStream_t stream) {
    const float* x      = (const float*)d_in[0];
    const int*   edge   = (const int*)d_in[1];
    const float* ee     = (const float*)d_in[2];
    const int*   edgenh = (const int*)d_in[3];
    const float* eenh   = (const float*)d_in[4];
    const float* a      = (const float*)d_in[5];
    const float* a2     = (const float*)d_in[6];
    const float* mlpw   = (const float*)d_in[7];
    const float* mlpb   = (const float*)d_in[8];

    float* ws     = (float*)d_ws;
    float* vall   = ws + VALL_OFF;
    float* wall   = ws + WALL_OFF;
    float* scal   = ws + SCAL_OFF;
    float* Xs     = ws + XS_OFF;
    float* rowsum = ws + RS_OFF;
    float* T      = ws + T_OFF;

    // zero rowsum + T (contiguous region)
    hipMemsetAsync(rowsum, 0, (size_t)(NN + NN * 400) * sizeof(float), stream);

    k_coeffs<<<3, 256, 0, stream>>>(a, a2, mlpw, vall, wall);

    dim3 gg(4, (NN + 63) / 64);
    k_gemm_xs<<<gg, 256, 0, stream>>>(x, a, Xs);

    k_node_scal<<<NN / 4, 256, 0, stream>>>(x, vall, wall, scal);

    k_edge<<<EN / 4, 256, 0, stream>>>(edge, ee, edgenh, eenh, x, vall, wall,
                                       scal, mlpb, rowsum, T);

    k_gemm_out<<<gg, 256, 0, stream>>>(T, a + 200, Xs, rowsum, (float*)d_out);
}

// Round 2
// 821.923 us; speedup vs baseline: 1.7877x; 1.7877x over previous
//
#include <hip/hip_runtime.h>
#include <math.h>

#define NN    50000
#define FDIM  200
#define E1N   400000
#define E2N   100000
#define EN    500000

typedef __attribute__((ext_vector_type(8))) short short8;
typedef __attribute__((ext_vector_type(4))) float f32x4;

// ---------------- workspace layout (float/int units, 4B) ----------------
#define VALL_OFF   0            // 600 f
#define WALL_OFF   608          // 600 f
#define SCAL_OFF   1216         // NN*4 f
#define XS_OFF     201216       // NN*200 f
#define RS_OFF     10201216     // NN f
#define CNT_OFF    10251216     // NN int   (zeroed)
#define FILL_OFF   10301216     // NN int   (zeroed)
#define INCL_OFF   10351216     // NN int
#define BSUM_OFF   10401216     // 256 int
#define SORT_OFF   10401472     // EN int
#define XB_OFF     10901472     // NN*200 bf16 = 5,000,000 f
#define AB_OFF     15901472     // 200*600 bf16 = 60,000 f
#define TB_OFF     15961472     // NN*400 bf16 = 10,000,000 f
// total ~25,961,472 floats = ~104 MB

static __device__ __forceinline__ unsigned short f2bf(float f) {
    unsigned int u = __float_as_uint(f);
    unsigned int r = (u + 0x7fffu + ((u >> 16) & 1u)) >> 16;
    return (unsigned short)r;
}

// v_all[k] = sum_o a_2[o]*a[o][k] ; w_all[k] = sum_o mlp_w[o]*a[o][k]
__global__ void k_coeffs(const float* __restrict__ a, const float* __restrict__ a2,
                         const float* __restrict__ mlpw,
                         float* __restrict__ vall, float* __restrict__ wall) {
    int k = blockIdx.x * blockDim.x + threadIdx.x;
    if (k >= 600) return;
    float v = 0.f, w = 0.f;
    for (int o = 0; o < FDIM; ++o) {
        float av = a[o * 600 + k];
        v += a2[o] * av;
        w += mlpw[o] * av;
    }
    vall[k] = v;
    wall[k] = w;
}

// per-node scalars ps,pd,qs,qd
__global__ __launch_bounds__(256) void k_node_scal(const float* __restrict__ x,
                                                   const float* __restrict__ vall,
                                                   const float* __restrict__ wall,
                                                   float* __restrict__ scal) {
    __shared__ float sv[1200];
    int tid = threadIdx.x;
    for (int i = tid; i < 1200; i += 256) sv[i] = (i < 600) ? vall[i] : wall[i - 600];
    __syncthreads();
    int lane = tid & 63;
    int n = blockIdx.x * 4 + (tid >> 6);
    float ps = 0.f, pd = 0.f, qs = 0.f, qd = 0.f;
    for (int k = lane; k < FDIM; k += 64) {
        float xv = x[(size_t)n * FDIM + k];
        ps += xv * sv[k];
        pd += xv * sv[200 + k];
        qs += xv * sv[600 + k];
        qd += xv * sv[800 + k];
    }
    #pragma unroll
    for (int off = 32; off > 0; off >>= 1) {
        ps += __shfl_xor(ps, off);
        pd += __shfl_xor(pd, off);
        qs += __shfl_xor(qs, off);
        qd += __shfl_xor(qd, off);
    }
    if (lane == 0) {
        float4 r = make_float4(ps, pd, qs, qd);
        *(float4*)(scal + (size_t)n * 4) = r;
    }
}

// fp32 -> bf16 conversion
__global__ __launch_bounds__(256) void k_cvt(const float* __restrict__ src,
                                             unsigned short* __restrict__ dst, int n4) {
    int i = blockIdx.x * 256 + threadIdx.x;
    if (i >= n4) return;
    float4 v = *(const float4*)(src + (size_t)i * 4);
    ushort4 o;
    o.x = f2bf(v.x); o.y = f2bf(v.y); o.z = f2bf(v.z); o.w = f2bf(v.w);
    *(ushort4*)(dst + (size_t)i * 4) = o;
}

// histogram of src node degrees
__global__ __launch_bounds__(256) void k_hist(const int* __restrict__ edge,
                                              const int* __restrict__ edgenh,
                                              int* __restrict__ counts) {
    int g = blockIdx.x * 256 + threadIdx.x;
    if (g >= EN) return;
    int s = (g < E1N) ? edge[g] : edgenh[g - E1N];
    atomicAdd(counts + s, 1);
}

__global__ __launch_bounds__(256) void k_scan1(const int* __restrict__ counts,
                                               int* __restrict__ incl,
                                               int* __restrict__ bsums) {
    __shared__ int tmp[256];
    int g = blockIdx.x * 256 + threadIdx.x;
    int v = (g < NN) ? counts[g] : 0;
    tmp[threadIdx.x] = v;
    __syncthreads();
    for (int off = 1; off < 256; off <<= 1) {
        int t = (threadIdx.x >= off) ? tmp[threadIdx.x - off] : 0;
        __syncthreads();
        tmp[threadIdx.x] += t;
        __syncthreads();
    }
    if (g < NN) incl[g] = tmp[threadIdx.x];
    if (threadIdx.x == 255) bsums[blockIdx.x] = tmp[255];
}

__global__ __launch_bounds__(256) void k_scan2(int* __restrict__ bsums, int nb) {
    __shared__ int tmp[256];
    int v = (threadIdx.x < nb) ? bsums[threadIdx.x] : 0;
    tmp[threadIdx.x] = v;
    __syncthreads();
    for (int off = 1; off < 256; off <<= 1) {
        int t = (threadIdx.x >= off) ? tmp[threadIdx.x - off] : 0;
        __syncthreads();
        tmp[threadIdx.x] += t;
        __syncthreads();
    }
    if (threadIdx.x < nb) bsums[threadIdx.x] = tmp[threadIdx.x] - v;  // exclusive
}

// offsets (exclusive) into incl's place? -> write into counts' sibling: offs = incl - counts + bsums[b]
__global__ __launch_bounds__(256) void k_scan3(const int* __restrict__ counts,
                                               int* __restrict__ incl,
                                               const int* __restrict__ bsums) {
    int g = blockIdx.x * 256 + threadIdx.x;
    if (g >= NN) return;
    incl[g] = incl[g] - counts[g] + bsums[blockIdx.x];  // incl becomes exclusive offsets
}

__global__ __launch_bounds__(256) void k_scatter(const int* __restrict__ edge,
                                                 const int* __restrict__ edgenh,
                                                 const int* __restrict__ offs,
                                                 int* __restrict__ fill,
                                                 int* __restrict__ sorted) {
    int g = blockIdx.x * 256 + threadIdx.x;
    if (g >= EN) return;
    int s = (g < E1N) ? edge[g] : edgenh[g - E1N];
    int pos = offs[s] + atomicAdd(fill + s, 1);
    sorted[pos] = g;
}

// one wave per node: compute edge weights, accumulate sum(w*x[dst]) and sum(w*emb),
// write T row (bf16) once + rowsum once. No atomics.
__global__ __launch_bounds__(256) void k_csr(const int* __restrict__ sorted,
                                             const int* __restrict__ offs,
                                             const int* __restrict__ counts,
                                             const int* __restrict__ edge,
                                             const int* __restrict__ edgenh,
                                             const float* __restrict__ ee,
                                             const float* __restrict__ eenh,
                                             const float* __restrict__ x,
                                             const float* __restrict__ vall,
                                             const float* __restrict__ wall,
                                             const float* __restrict__ scal,
                                             const float* __restrict__ mlpb,
                                             float* __restrict__ rowsum,
                                             unsigned short* __restrict__ Tb) {
    int tid = threadIdx.x, lane = tid & 63;
    int n = blockIdx.x * 4 + (tid >> 6);
    float4 v3 = make_float4(0, 0, 0, 0), w3 = v3;
    if (lane < 50) {
        v3 = *(const float4*)(vall + 400 + lane * 4);
        w3 = *(const float4*)(wall + 400 + lane * 4);
    }
    float4 sc_n = *(const float4*)(scal + (size_t)n * 4);
    float mb = mlpb[0];
    int beg = offs[n], cnt = counts[n];
    float accx0 = 0, accx1 = 0, accx2 = 0, accx3 = 0;
    float acce0 = 0, acce1 = 0, acce2 = 0, acce3 = 0;
    float rs = 0.f;
    for (int i = 0; i < cnt; ++i) {
        int e = sorted[beg + i];
        int d;
        const float* erow;
        if (e < E1N) { d = edge[E1N + e]; erow = ee + (size_t)e * FDIM; }
        else { int e2 = e - E1N; d = edgenh[E2N + e2]; erow = eenh + (size_t)e2 * FDIM; }
        float4 ev = make_float4(0, 0, 0, 0), xv = ev;
        if (lane < 50) {
            ev = *(const float4*)(erow + lane * 4);
            xv = *(const float4*)(x + (size_t)d * FDIM + lane * 4);
        }
        float pe = ev.x * v3.x + ev.y * v3.y + ev.z * v3.z + ev.w * v3.w;
        float qe = ev.x * w3.x + ev.y * w3.y + ev.z * w3.z + ev.w * w3.w;
        #pragma unroll
        for (int off = 32; off > 0; off >>= 1) {
            pe += __shfl_xor(pe, off);
            qe += __shfl_xor(qe, off);
        }
        float4 sd = *(const float4*)(scal + (size_t)d * 4);
        float z1 = sc_n.x + sd.y + pe;
        float z2 = sc_n.z + sd.w + qe + mb;
        float l = z1 > 0.f ? z1 : 0.2f * z1;
        float wgt = expf((-l) * tanhf(z2) * (1.0f / (float)EN));
        rs += wgt;
        accx0 += wgt * xv.x; accx1 += wgt * xv.y; accx2 += wgt * xv.z; accx3 += wgt * xv.w;
        acce0 += wgt * ev.x; acce1 += wgt * ev.y; acce2 += wgt * ev.z; acce3 += wgt * ev.w;
    }
    if (lane == 0) rowsum[n] = rs;
    if (lane < 50) {
        ushort4 o1, o2;
        o1.x = f2bf(accx0); o1.y = f2bf(accx1); o1.z = f2bf(accx2); o1.w = f2bf(accx3);
        o2.x = f2bf(acce0); o2.y = f2bf(acce1); o2.z = f2bf(acce2); o2.w = f2bf(acce3);
        *(ushort4*)(Tb + (size_t)n * 400 + lane * 4) = o1;
        *(ushort4*)(Tb + (size_t)n * 400 + 200 + lane * 4) = o2;
    }
}

// C[M x 200] = A[M x KREAL] @ B[200 x KREAL]^T  (bf16 in, fp32 out) via MFMA.
// FINAL: out = elu(Xs + C/rowsum), rowsum==0 -> 0.
template <int KPAD, int KREAL, int LDA, int LDB, bool FINAL>
__global__ __launch_bounds__(256) void k_mfma(const unsigned short* __restrict__ A,
                                              const unsigned short* __restrict__ B,
                                              const float* __restrict__ Xs,
                                              const float* __restrict__ rowsum,
                                              float* __restrict__ C) {
    __shared__ unsigned short Al[64][40];
    __shared__ unsigned short Bl[64][40];
    int tid = threadIdx.x, w = tid >> 6, lane = tid & 63;
    int bx = blockIdx.x, by = blockIdx.y;
    f32x4 acc[4] = {};
    int r = tid >> 2, c = tid & 3;
    for (int k0 = 0; k0 < KPAD; k0 += 32) {
        int gk = k0 + c * 8;
        uint4 av = make_uint4(0, 0, 0, 0), bv = av;
        int arow = by * 64 + r;
        if (arow < NN && gk < KREAL)
            av = *(const uint4*)(A + (size_t)arow * LDA + gk);
        int brow = bx * 64 + r;
        if (brow < 200 && gk < KREAL)
            bv = *(const uint4*)(B + (size_t)brow * LDB + gk);
        *(uint4*)&Al[r][c * 8] = av;
        *(uint4*)&Bl[r][c * 8] = bv;
        __syncthreads();
        short8 af = *(short8*)&Al[w * 16 + (lane & 15)][(lane >> 4) * 8];
        #pragma unroll
        for (int ct = 0; ct < 4; ++ct) {
            short8 bf = *(short8*)&Bl[ct * 16 + (lane & 15)][(lane >> 4) * 8];
            acc[ct] = __builtin_amdgcn_mfma_f32_16x16x32_bf16(af, bf, acc[ct], 0, 0, 0);
        }
        __syncthreads();
    }
    #pragma unroll
    for (int ct = 0; ct < 4; ++ct) {
        #pragma unroll
        for (int rr = 0; rr < 4; ++rr) {
            int grow = by * 64 + w * 16 + (lane >> 4) * 4 + rr;
            int gcol = bx * 64 + ct * 16 + (lane & 15);
            if (grow < NN && gcol < 200) {
                float v = acc[ct][rr];
                if (FINAL) {
                    float rsv = rowsum[grow];
                    float o;
                    if (rsv == 0.f) o = 0.f;
                    else {
                        float h = Xs[(size_t)grow * 200 + gcol] + v / rsv;
                        o = h > 0.f ? h : expm1f(h);
                    }
                    C[(size_t)grow * 200 + gcol] = o;
                } else {
                    C[(size_t)grow * 200 + gcol] = v;
                }
            }
        }
    }
}

extern "C" void kernel_launch(void* const* d_in, const int* in_sizes, int n_in,
                              void* d_out, int out_size, void* d_ws, size_t ws_size,
                              hipStream_t stream) {
    const float* x      = (const float*)d_in[0];
    const int*   edge   = (const int*)d_in[1];
    const float* ee     = (const float*)d_in[2];
    const int*   edgenh = (const int*)d_in[3];
    const float* eenh   = (const float*)d_in[4];
    const float* a      = (const float*)d_in[5];
    const float* a2     = (const float*)d_in[6];
    const float* mlpw   = (const float*)d_in[7];
    const float* mlpb   = (const float*)d_in[8];

    float* ws = (float*)d_ws;
    float* vall   = ws + VALL_OFF;
    float* wall   = ws + WALL_OFF;
    float* scal   = ws + SCAL_OFF;
    float* Xs     = ws + XS_OFF;
    float* rowsum = ws + RS_OFF;
    int*   counts = (int*)(ws + CNT_OFF);
    int*   fill   = (int*)(ws + FILL_OFF);
    int*   incl   = (int*)(ws + INCL_OFF);
    int*   bsums  = (int*)(ws + BSUM_OFF);
    int*   sorted = (int*)(ws + SORT_OFF);
    unsigned short* xb = (unsigned short*)(ws + XB_OFF);
    unsigned short* ab = (unsigned short*)(ws + AB_OFF);
    unsigned short* Tb = (unsigned short*)(ws + TB_OFF);

    // zero counts + fill (contiguous)
    hipMemsetAsync(counts, 0, (size_t)(2 * NN) * sizeof(int), stream);

    k_coeffs<<<3, 256, 0, stream>>>(a, a2, mlpw, vall, wall);
    k_node_scal<<<NN / 4, 256, 0, stream>>>(x, vall, wall, scal);

    k_cvt<<<(NN * FDIM / 4 + 255) / 256, 256, 0, stream>>>(x, xb, NN * FDIM / 4);
    k_cvt<<<(200 * 600 / 4 + 255) / 256, 256, 0, stream>>>(a, ab, 200 * 600 / 4);

    k_hist<<<(EN + 255) / 256, 256, 0, stream>>>(edge, edgenh, counts);
    int nb = (NN + 255) / 256;  // 196
    k_scan1<<<nb, 256, 0, stream>>>(counts, incl, bsums);
    k_scan2<<<1, 256, 0, stream>>>(bsums, nb);
    k_scan3<<<nb, 256, 0, stream>>>(counts, incl, bsums);  // incl -> exclusive offsets
    k_scatter<<<(EN + 255) / 256, 256, 0, stream>>>(edge, edgenh, incl, fill, sorted);

    dim3 gg(4, (NN + 63) / 64);
    k_mfma<224, 200, 200, 600, false><<<gg, 256, 0, stream>>>(xb, ab, nullptr, nullptr, Xs);

    k_csr<<<NN / 4, 256, 0, stream>>>(sorted, incl, counts, edge, edgenh, ee, eenh,
                                      x, vall, wall, scal, mlpb, rowsum, Tb);

    k_mfma<416, 400, 400, 600, true><<<gg, 256, 0, stream>>>(Tb, ab + 200, Xs, rowsum,
                                                             (float*)d_out);
}

// Round 4
// 746.446 us; speedup vs baseline: 1.9685x; 1.1011x over previous
//
#include <hip/hip_runtime.h>
#include <math.h>

#define NN    50000
#define FDIM  200
#define E1N   400000
#define E2N   100000
#define EN    500000

typedef __attribute__((ext_vector_type(8))) short short8;
typedef __attribute__((ext_vector_type(4))) float f32x4;

// ---------------- workspace layout (4B units) ----------------
#define VALL_OFF   0            // 600 f
#define WALL_OFF   608          // 600 f
#define SCAL_OFF   1216         // NN*4 f = 200,000
#define RS_OFF     201216       // NN f
#define CNT_OFF    251216       // NN int (zeroed)
#define FILL_OFF   301216       // NN int (zeroed, then = offsets)
#define INCL_OFF   351216       // NN int (offsets)
#define BSUM_OFF   401216       // 256 int
#define SORT_OFF   401472       // EN int2 = 1,000,000 ints
#define XB_OFF     1401472      // NN*200 bf16 = 10,000,000 ushort = 5,000,000 f
#define AB_OFF     6401472      // 200*600 bf16 = 120,000 ushort = 60,000 f
#define TSB_OFF    6461472      // NN*400 bf16 = 20,000,000 ushort = 10,000,000 f
// total 16,461,472 floats = ~66 MB

static __device__ __forceinline__ unsigned short f2bf(float f) {
    unsigned int u = __float_as_uint(f);
    unsigned int r = (u + 0x7fffu + ((u >> 16) & 1u)) >> 16;
    return (unsigned short)r;
}
static __device__ __forceinline__ float bf2f(unsigned short s) {
    return __uint_as_float((unsigned int)s << 16);
}

__global__ void k_coeffs(const float* __restrict__ a, const float* __restrict__ a2,
                         const float* __restrict__ mlpw,
                         float* __restrict__ vall, float* __restrict__ wall) {
    int k = blockIdx.x * blockDim.x + threadIdx.x;
    if (k >= 600) return;
    float v = 0.f, w = 0.f;
    for (int o = 0; o < FDIM; ++o) {
        float av = a[o * 600 + k];
        v += a2[o] * av;
        w += mlpw[o] * av;
    }
    vall[k] = v;
    wall[k] = w;
}

// per-node scalars ps,pd,qs,qd + fused x->bf16 conversion
__global__ __launch_bounds__(256) void k_node_scal(const float* __restrict__ x,
                                                   const float* __restrict__ vall,
                                                   const float* __restrict__ wall,
                                                   float* __restrict__ scal,
                                                   unsigned short* __restrict__ xb) {
    __shared__ float sv[1200];
    int tid = threadIdx.x;
    for (int i = tid; i < 1200; i += 256) sv[i] = (i < 600) ? vall[i] : wall[i - 600];
    __syncthreads();
    int lane = tid & 63;
    int n = blockIdx.x * 4 + (tid >> 6);
    float ps = 0.f, pd = 0.f, qs = 0.f, qd = 0.f;
    if (lane < 50) {
        float4 xv = *(const float4*)(x + (size_t)n * FDIM + lane * 4);
        float4 v1 = *(const float4*)(sv + lane * 4);
        float4 v2 = *(const float4*)(sv + 200 + lane * 4);
        float4 w1 = *(const float4*)(sv + 600 + lane * 4);
        float4 w2 = *(const float4*)(sv + 800 + lane * 4);
        ps = xv.x * v1.x + xv.y * v1.y + xv.z * v1.z + xv.w * v1.w;
        pd = xv.x * v2.x + xv.y * v2.y + xv.z * v2.z + xv.w * v2.w;
        qs = xv.x * w1.x + xv.y * w1.y + xv.z * w1.z + xv.w * w1.w;
        qd = xv.x * w2.x + xv.y * w2.y + xv.z * w2.z + xv.w * w2.w;
        ushort4 o;
        o.x = f2bf(xv.x); o.y = f2bf(xv.y); o.z = f2bf(xv.z); o.w = f2bf(xv.w);
        *(ushort4*)(xb + (size_t)n * FDIM + lane * 4) = o;
    }
    #pragma unroll
    for (int off = 32; off > 0; off >>= 1) {
        ps += __shfl_xor(ps, off);
        pd += __shfl_xor(pd, off);
        qs += __shfl_xor(qs, off);
        qd += __shfl_xor(qd, off);
    }
    if (lane == 0) {
        float4 r = make_float4(ps, pd, qs, qd);
        *(float4*)(scal + (size_t)n * 4) = r;
    }
}

__global__ __launch_bounds__(256) void k_cvt(const float* __restrict__ src,
                                             unsigned short* __restrict__ dst, int n4) {
    int i = blockIdx.x * 256 + threadIdx.x;
    if (i >= n4) return;
    float4 v = *(const float4*)(src + (size_t)i * 4);
    ushort4 o;
    o.x = f2bf(v.x); o.y = f2bf(v.y); o.z = f2bf(v.z); o.w = f2bf(v.w);
    *(ushort4*)(dst + (size_t)i * 4) = o;
}

__global__ __launch_bounds__(256) void k_hist(const int* __restrict__ edge,
                                              const int* __restrict__ edgenh,
                                              int* __restrict__ counts) {
    int g = blockIdx.x * 256 + threadIdx.x;
    if (g >= EN) return;
    int s = (g < E1N) ? edge[g] : edgenh[g - E1N];
    atomicAdd(counts + s, 1);
}

__global__ __launch_bounds__(256) void k_scan1(const int* __restrict__ counts,
                                               int* __restrict__ incl,
                                               int* __restrict__ bsums) {
    __shared__ int tmp[256];
    int g = blockIdx.x * 256 + threadIdx.x;
    int v = (g < NN) ? counts[g] : 0;
    tmp[threadIdx.x] = v;
    __syncthreads();
    for (int off = 1; off < 256; off <<= 1) {
        int t = (threadIdx.x >= off) ? tmp[threadIdx.x - off] : 0;
        __syncthreads();
        tmp[threadIdx.x] += t;
        __syncthreads();
    }
    if (g < NN) incl[g] = tmp[threadIdx.x];
    if (threadIdx.x == 255) bsums[blockIdx.x] = tmp[255];
}

__global__ __launch_bounds__(256) void k_scan2(int* __restrict__ bsums, int nb) {
    __shared__ int tmp[256];
    int v = (threadIdx.x < nb) ? bsums[threadIdx.x] : 0;
    tmp[threadIdx.x] = v;
    __syncthreads();
    for (int off = 1; off < 256; off <<= 1) {
        int t = (threadIdx.x >= off) ? tmp[threadIdx.x - off] : 0;
        __syncthreads();
        tmp[threadIdx.x] += t;
        __syncthreads();
    }
    if (threadIdx.x < nb) bsums[threadIdx.x] = tmp[threadIdx.x] - v;  // exclusive
}

// incl -> exclusive offsets; also copy into fill (running cursor for scatter)
__global__ __launch_bounds__(256) void k_scan3(const int* __restrict__ counts,
                                               int* __restrict__ incl,
                                               const int* __restrict__ bsums,
                                               int* __restrict__ fill) {
    int g = blockIdx.x * 256 + threadIdx.x;
    if (g >= NN) return;
    int v = incl[g] - counts[g] + bsums[blockIdx.x];
    incl[g] = v;
    fill[g] = v;
}

// scatter (e, dst) pairs grouped by src
__global__ __launch_bounds__(256) void k_scatter(const int* __restrict__ edge,
                                                 const int* __restrict__ edgenh,
                                                 int* __restrict__ fill,
                                                 int2* __restrict__ sorted2) {
    int g = blockIdx.x * 256 + threadIdx.x;
    if (g >= EN) return;
    int s, d;
    if (g < E1N) { s = edge[g]; d = edge[E1N + g]; }
    else { s = edgenh[g - E1N]; d = edgenh[E2N + (g - E1N)]; }
    int pos = atomicAdd(fill + s, 1);
    sorted2[pos] = make_int2(g, d);
}

// one wave per node: weights + accumulation; writes T/rs (bf16) + rowsum. No atomics.
__global__ __launch_bounds__(256) void k_csr(const int2* __restrict__ sorted2,
                                             const int* __restrict__ offs,
                                             const int* __restrict__ counts,
                                             const float* __restrict__ ee,
                                             const float* __restrict__ eenh,
                                             const unsigned short* __restrict__ xb,
                                             const float* __restrict__ vall,
                                             const float* __restrict__ wall,
                                             const float* __restrict__ scal,
                                             const float* __restrict__ mlpb,
                                             float* __restrict__ rowsum,
                                             unsigned short* __restrict__ Tsb) {
    int tid = threadIdx.x, lane = tid & 63;
    int n = blockIdx.x * 4 + (tid >> 6);
    float4 v3 = make_float4(0, 0, 0, 0), w3 = v3;
    if (lane < 50) {
        v3 = *(const float4*)(vall + 400 + lane * 4);
        w3 = *(const float4*)(wall + 400 + lane * 4);
    }
    float4 sc_n = *(const float4*)(scal + (size_t)n * 4);
    float mb = mlpb[0];
    int beg = offs[n], cnt = counts[n];
    float accx0 = 0, accx1 = 0, accx2 = 0, accx3 = 0;
    float acce0 = 0, acce1 = 0, acce2 = 0, acce3 = 0;
    float rs = 0.f;
    int2 ed = (cnt > 0) ? sorted2[beg] : make_int2(0, 0);
    for (int i = 0; i < cnt; ++i) {
        int2 ed_n = (i + 1 < cnt) ? sorted2[beg + i + 1] : ed;  // prefetch
        int e = ed.x, d = ed.y;
        const float* erow = (e < E1N) ? ee + (size_t)e * FDIM
                                      : eenh + (size_t)(e - E1N) * FDIM;
        float4 ev = make_float4(0, 0, 0, 0), xv = ev;
        if (lane < 50) {
            ev = *(const float4*)(erow + lane * 4);
            ushort4 xu = *(const ushort4*)(xb + (size_t)d * FDIM + lane * 4);
            xv.x = bf2f(xu.x); xv.y = bf2f(xu.y); xv.z = bf2f(xu.z); xv.w = bf2f(xu.w);
        }
        float pe = ev.x * v3.x + ev.y * v3.y + ev.z * v3.z + ev.w * v3.w;
        float qe = ev.x * w3.x + ev.y * w3.y + ev.z * w3.z + ev.w * w3.w;
        #pragma unroll
        for (int off = 32; off > 0; off >>= 1) {
            pe += __shfl_xor(pe, off);
            qe += __shfl_xor(qe, off);
        }
        float4 sd = *(const float4*)(scal + (size_t)d * 4);
        float z1 = sc_n.x + sd.y + pe;
        float z2 = sc_n.z + sd.w + qe + mb;
        float l = z1 > 0.f ? z1 : 0.2f * z1;
        float e2 = __expf(2.f * z2);
        float t = 1.f - 2.f * __builtin_amdgcn_rcpf(e2 + 1.f);
        float wgt = __expf(l * t * (-1.f / (float)EN));
        rs += wgt;
        accx0 += wgt * xv.x; accx1 += wgt * xv.y; accx2 += wgt * xv.z; accx3 += wgt * xv.w;
        acce0 += wgt * ev.x; acce1 += wgt * ev.y; acce2 += wgt * ev.z; acce3 += wgt * ev.w;
        ed = ed_n;
    }
    if (lane == 0) rowsum[n] = rs;
    float inv = (cnt > 0) ? __builtin_amdgcn_rcpf(rs) : 0.f;
    if (lane < 50) {
        ushort4 o1, o2;
        o1.x = f2bf(accx0 * inv); o1.y = f2bf(accx1 * inv);
        o1.z = f2bf(accx2 * inv); o1.w = f2bf(accx3 * inv);
        o2.x = f2bf(acce0 * inv); o2.y = f2bf(acce1 * inv);
        o2.z = f2bf(acce2 * inv); o2.w = f2bf(acce3 * inv);
        *(ushort4*)(Tsb + (size_t)n * 400 + lane * 4) = o1;
        *(ushort4*)(Tsb + (size_t)n * 400 + 200 + lane * 4) = o2;
    }
}

// single fused GEMM: out = elu([x | T/rs] @ A^T), rowsum==0 -> 0
// K padded to 640: [0,200) from xb, [224,624) from Tsb, rest zero. B from ab (stride 600).
__global__ __launch_bounds__(256) void k_gemm_fused(const unsigned short* __restrict__ xb,
                                                    const unsigned short* __restrict__ tsb,
                                                    const unsigned short* __restrict__ ab,
                                                    const float* __restrict__ rowsum,
                                                    float* __restrict__ out) {
    __shared__ unsigned short Al[64][40];
    __shared__ unsigned short Bl[64][40];
    int tid = threadIdx.x, w = tid >> 6, lane = tid & 63;
    int bx = blockIdx.x, by = blockIdx.y;
    f32x4 acc[4] = {};
    int r = tid >> 2, c = tid & 3;
    int arow = by * 64 + r;
    int brow = bx * 64 + r;
    bool inA = arow < NN;
    bool inB = brow < 200;
    const unsigned short* aPx = xb + (size_t)arow * 200;
    const unsigned short* aPt = tsb + (size_t)arow * 400;
    const unsigned short* bP = ab + (size_t)brow * 600;
    for (int k0 = 0; k0 < 640; k0 += 32) {
        int gk = k0 + c * 8;
        uint4 av = make_uint4(0, 0, 0, 0), bv = av;
        if (gk < 200) {
            if (inA) av = *(const uint4*)(aPx + gk);
            if (inB) bv = *(const uint4*)(bP + gk);
        } else if (gk >= 224 && gk < 624) {
            if (inA) av = *(const uint4*)(aPt + (gk - 224));
            if (inB) bv = *(const uint4*)(bP + gk - 24);  // a col 200 + (gk-224)
        }
        *(uint4*)&Al[r][c * 8] = av;
        *(uint4*)&Bl[r][c * 8] = bv;
        __syncthreads();
        short8 af = *(short8*)&Al[w * 16 + (lane & 15)][(lane >> 4) * 8];
        #pragma unroll
        for (int ct = 0; ct < 4; ++ct) {
            short8 bf = *(short8*)&Bl[ct * 16 + (lane & 15)][(lane >> 4) * 8];
            acc[ct] = __builtin_amdgcn_mfma_f32_16x16x32_bf16(af, bf, acc[ct], 0, 0, 0);
        }
        __syncthreads();
    }
    #pragma unroll
    for (int ct = 0; ct < 4; ++ct) {
        #pragma unroll
        for (int rr = 0; rr < 4; ++rr) {
            int grow = by * 64 + w * 16 + (lane >> 4) * 4 + rr;
            int gcol = bx * 64 + ct * 16 + (lane & 15);
            if (grow < NN && gcol < 200) {
                float rsv = rowsum[grow];
                float h = acc[ct][rr];
                float o = (rsv == 0.f) ? 0.f : (h > 0.f ? h : expm1f(h));
                out[(size_t)grow * 200 + gcol] = o;
            }
        }
    }
}

extern "C" void kernel_launch(void* const* d_in, const int* in_sizes, int n_in,
                              void* d_out, int out_size, void* d_ws, size_t ws_size,
                              hipStream_t stream) {
    const float* x      = (const float*)d_in[0];
    const int*   edge   = (const int*)d_in[1];
    const float* ee     = (const float*)d_in[2];
    const int*   edgenh = (const int*)d_in[3];
    const float* eenh   = (const float*)d_in[4];
    const float* a      = (const float*)d_in[5];
    const float* a2     = (const float*)d_in[6];
    const float* mlpw   = (const float*)d_in[7];
    const float* mlpb   = (const float*)d_in[8];

    float* ws = (float*)d_ws;
    float* vall   = ws + VALL_OFF;
    float* wall   = ws + WALL_OFF;
    float* scal   = ws + SCAL_OFF;
    float* rowsum = ws + RS_OFF;
    int*   counts = (int*)(ws + CNT_OFF);
    int*   fill   = (int*)(ws + FILL_OFF);
    int*   incl   = (int*)(ws + INCL_OFF);
    int*   bsums  = (int*)(ws + BSUM_OFF);
    int2*  sorted2 = (int2*)(ws + SORT_OFF);
    unsigned short* xb  = (unsigned short*)(ws + XB_OFF);
    unsigned short* ab  = (unsigned short*)(ws + AB_OFF);
    unsigned short* tsb = (unsigned short*)(ws + TSB_OFF);

    hipMemsetAsync(counts, 0, (size_t)(2 * NN) * sizeof(int), stream);

    k_coeffs<<<3, 256, 0, stream>>>(a, a2, mlpw, vall, wall);
    k_node_scal<<<NN / 4, 256, 0, stream>>>(x, vall, wall, scal, xb);
    k_cvt<<<(200 * 600 / 4 + 255) / 256, 256, 0, stream>>>(a, ab, 200 * 600 / 4);

    k_hist<<<(EN + 255) / 256, 256, 0, stream>>>(edge, edgenh, counts);
    int nb = (NN + 255) / 256;
    k_scan1<<<nb, 256, 0, stream>>>(counts, incl, bsums);
    k_scan2<<<1, 256, 0, stream>>>(bsums, nb);
    k_scan3<<<nb, 256, 0, stream>>>(counts, incl, bsums, fill);
    k_scatter<<<(EN + 255) / 256, 256, 0, stream>>>(edge, edgenh, fill, sorted2);

    k_csr<<<NN / 4, 256, 0, stream>>>(sorted2, incl, counts, ee, eenh, xb,
                                      vall, wall, scal, mlpb, rowsum, tsb);

    dim3 gg(4, (NN + 63) / 64);
    k_gemm_fused<<<gg, 256, 0, stream>>>(xb, tsb, ab, rowsum, (float*)d_out);
}